// Round 10
// baseline (446.276 us; speedup 1.0000x reference)
//
#include <hip/hip_runtime.h>
#include <math.h>

#define VOCAB 30000
#define EMB   100
#define HID   128
#define BATCH 1024
#define SEQ   512

typedef float f32x4 __attribute__((ext_vector_type(4)));

// Kernel A: EWx[v][j] = sum_e E[v][e]*Wx[e][j] + b[j]   (folds bias in)
__global__ __launch_bounds__(256) void ewx_kernel(
    const float* __restrict__ E, const float* __restrict__ Wx,
    const float* __restrict__ bias, float* __restrict__ EWx)
{
    __shared__ float Es[64][EMB];     // 25.6 KB
    __shared__ float Wxs[EMB][HID];   // 51.2 KB
    const int tid = threadIdx.x;
    const int v0 = blockIdx.x * 64;
    const int nv = min(64, VOCAB - v0);

    {
        const float4* s4 = (const float4*)Wx;
        float4* d4 = (float4*)(&Wxs[0][0]);
        for (int i = tid; i < (EMB * HID) / 4; i += 256) d4[i] = s4[i];
    }
    {
        const float* src = E + (size_t)v0 * EMB;
        float* dst = &Es[0][0];
        const int n  = nv * EMB;
        const int n4 = n >> 2;
        const float4* s4 = (const float4*)src;
        float4* d4 = (float4*)dst;
        for (int i = tid; i < n4; i += 256) d4[i] = s4[i];
        for (int i = (n4 << 2) + tid; i < n; i += 256) dst[i] = src[i];
    }
    __syncthreads();

    const int j  = tid & 127;
    const int vh = tid >> 7;
    float acc[32];
#pragma unroll
    for (int m = 0; m < 32; ++m) acc[m] = 0.f;

    for (int k4 = 0; k4 < EMB; k4 += 4) {
        const float w0 = Wxs[k4 + 0][j];
        const float w1 = Wxs[k4 + 1][j];
        const float w2 = Wxs[k4 + 2][j];
        const float w3 = Wxs[k4 + 3][j];
#pragma unroll
        for (int m = 0; m < 32; ++m) {
            const float4 e = *(const float4*)&Es[vh + 2 * m][k4];
            acc[m] = fmaf(e.x, w0, acc[m]);
            acc[m] = fmaf(e.y, w1, acc[m]);
            acc[m] = fmaf(e.z, w2, acc[m]);
            acc[m] = fmaf(e.w, w3, acc[m]);
        }
    }
    const float bj = bias[j];
#pragma unroll
    for (int m = 0; m < 32; ++m) {
        const int v = vh + 2 * m;
        if (v < nv)
            EWx[(size_t)(v0 + v) * HID + j] = acc[m] + bj;
    }
}

// Kernel B: sequential recurrence. 256 thr, 2 rows/block, grid 512 =
// 2 blocks/CU, weu(2,2) — the r6/r9-PROVEN weight-residency config
// (VGPR 88 both rounds). r6/r9 were latency-bound (VALUBusy ~50%,
// ~1900 cyc/step vs ~600 issue) — this round shortens the serial chain:
//  1. gather pipeline 2 steps deep: token LDS-read and EWx gather each
//     issued 2 steps before use (manually unrolled x2, rotating regs).
//  2. kq-LSB folded in-wave via shfl_xor(32) -> only a 4-way LDS part
//     reduce (was 8-way): half the part traffic and finalize reads.
//  3. single hbuf (2 barriers/step already order write->read), no flip.
// Thread = (kq = tid>>5 in 0..7, jc = tid&31): Wh[16kq..+16)[4jc..4jc+3]
// = 64 weights in named scalars + pins; partials for BOTH rows = 128 FMA.
__global__ __launch_bounds__(256)
__attribute__((amdgpu_waves_per_eu(2, 2)))
void rnn_kernel(
    const int* __restrict__ X, const float* __restrict__ EWx,
    const float* __restrict__ Wh, const float* __restrict__ Wd,
    const float* __restrict__ bd, float* __restrict__ out)
{
    __shared__ __align__(16) float hbuf[2][HID];      // [row][col], 1 KB
    __shared__ __align__(16) float part[2][4][HID];   // [row][kqp][col], 4 KB
    __shared__ int idx[2][SEQ];                       // 4 KB

    const int tid = threadIdx.x;
    const int kq  = tid >> 5;          // k-slice [16kq, 16kq+16)
    const int jc  = tid & 31;          // cols 4jc..4jc+3
    const int b0  = blockIdx.x * 2;

    for (int i = tid; i < 2 * SEQ; i += 256)
        idx[i >> 9][i & 511] = X[(size_t)(b0 + (i >> 9)) * SEQ + (i & 511)];

    // 64 weights in named scalars: W{kk}_{c} = Wh[16kq+kk][4jc+c]
#define DECLW(kk) float W##kk##_0, W##kk##_1, W##kk##_2, W##kk##_3;
    DECLW(0)  DECLW(1)  DECLW(2)  DECLW(3)
    DECLW(4)  DECLW(5)  DECLW(6)  DECLW(7)
    DECLW(8)  DECLW(9)  DECLW(10) DECLW(11)
    DECLW(12) DECLW(13) DECLW(14) DECLW(15)
#undef DECLW
#define LOADW(kk) { const f32x4 w_ = *reinterpret_cast<const f32x4*>(      \
        &Wh[(size_t)(16 * kq + kk) * HID + 4 * jc]);                       \
        W##kk##_0 = w_.x; W##kk##_1 = w_.y;                                \
        W##kk##_2 = w_.z; W##kk##_3 = w_.w; }
    LOADW(0)  LOADW(1)  LOADW(2)  LOADW(3)
    LOADW(4)  LOADW(5)  LOADW(6)  LOADW(7)
    LOADW(8)  LOADW(9)  LOADW(10) LOADW(11)
    LOADW(12) LOADW(13) LOADW(14) LOADW(15)
#undef LOADW
#define PINW(kk) asm("" : "+v"(W##kk##_0), "+v"(W##kk##_1), \
                          "+v"(W##kk##_2), "+v"(W##kk##_3));
    PINW(0)  PINW(1)  PINW(2)  PINW(3)
    PINW(4)  PINW(5)  PINW(6)  PINW(7)
    PINW(8)  PINW(9)  PINW(10) PINW(11)
    PINW(12) PINW(13) PINW(14) PINW(15)
#undef PINW

    (&hbuf[0][0])[tid] = 0.f;          // h0 = 0 (256 floats = all of hbuf)
    __syncthreads();

    const int rf  = tid >> 7;          // row this thread finalizes
    const int cf  = tid & 127;         // column this thread finalizes
    const int kqp = kq >> 1;           // part slot after in-wave fold

    const f32x4* h0r = (const f32x4*)&hbuf[0][16 * kq];
    const f32x4* h1r = (const f32x4*)&hbuf[1][16 * kq];
    float* pw0 = &part[0][kqp][4 * jc];
    float* pw1 = &part[1][kqp][4 * jc];

    // gather pipeline, depth 2: xp{A,B} in flight, tk{A,B} tokens for t+2
    float xpA = EWx[(size_t)idx[rf][0] * HID + cf];
    float xpB = EWx[(size_t)idx[rf][1] * HID + cf];
    int   tkA = idx[rf][2];
    int   tkB = idx[rf][3];

#define FMAK(kk, hv0, hv1)                                                  \
        A00 = fmaf(hv0, W##kk##_0, A00); A01 = fmaf(hv0, W##kk##_1, A01);   \
        A02 = fmaf(hv0, W##kk##_2, A02); A03 = fmaf(hv0, W##kk##_3, A03);   \
        A10 = fmaf(hv1, W##kk##_0, A10); A11 = fmaf(hv1, W##kk##_1, A11);   \
        A12 = fmaf(hv1, W##kk##_2, A12); A13 = fmaf(hv1, W##kk##_3, A13);

#define STEP(XP, TK, TNEXT) {                                               \
        const float xp_use = XP;                                            \
        XP = EWx[(size_t)TK * HID + cf];      /* for step t+2 */            \
        TK = idx[rf][(TNEXT) < SEQ ? (TNEXT) : SEQ - 1]; /* for t+4 */      \
        const f32x4 u00 = h0r[0], u01 = h0r[1], u02 = h0r[2], u03 = h0r[3]; \
        const f32x4 u10 = h1r[0], u11 = h1r[1], u12 = h1r[2], u13 = h1r[3]; \
        float A00=0.f,A01=0.f,A02=0.f,A03=0.f;                              \
        float A10=0.f,A11=0.f,A12=0.f,A13=0.f;                              \
        FMAK(0,  u00.x, u10.x) FMAK(1,  u00.y, u10.y)                       \
        FMAK(2,  u00.z, u10.z) FMAK(3,  u00.w, u10.w)                       \
        FMAK(4,  u01.x, u11.x) FMAK(5,  u01.y, u11.y)                       \
        FMAK(6,  u01.z, u11.z) FMAK(7,  u01.w, u11.w)                       \
        FMAK(8,  u02.x, u12.x) FMAK(9,  u02.y, u12.y)                       \
        FMAK(10, u02.z, u12.z) FMAK(11, u02.w, u12.w)                       \
        FMAK(12, u03.x, u13.x) FMAK(13, u03.y, u13.y)                       \
        FMAK(14, u03.z, u13.z) FMAK(15, u03.w, u13.w)                       \
        /* fold kq LSB in-wave (partner lane ^32) */                        \
        A00 += __shfl_xor(A00, 32); A01 += __shfl_xor(A01, 32);             \
        A02 += __shfl_xor(A02, 32); A03 += __shfl_xor(A03, 32);             \
        A10 += __shfl_xor(A10, 32); A11 += __shfl_xor(A11, 32);             \
        A12 += __shfl_xor(A12, 32); A13 += __shfl_xor(A13, 32);             \
        if ((tid & 32) == 0) {              /* kq even: write pair sums */  \
            f32x4 p;                                                        \
            p.x = A00; p.y = A01; p.z = A02; p.w = A03;                     \
            *reinterpret_cast<f32x4*>(pw0) = p;                             \
            p.x = A10; p.y = A11; p.z = A12; p.w = A13;                     \
            *reinterpret_cast<f32x4*>(pw1) = p;                             \
        }                                                                   \
        __syncthreads();                                                    \
        /* finalize (rf, cf): 4-way reduce + xp + tanh */                   \
        const float s = xp_use + part[rf][0][cf] + part[rf][1][cf]          \
                               + part[rf][2][cf] + part[rf][3][cf];         \
        const float xv = fminf(fmaxf(s, -9.f), 9.f);                        \
        const float e2 = __expf(2.f * xv);                                  \
        hbuf[rf][cf] = __fdividef(e2 - 1.f, e2 + 1.f);                      \
        __syncthreads();                                                    \
    }

#pragma unroll 1
    for (int t = 0; t < SEQ; t += 2) {
        STEP(xpA, tkA, t + 4)
        STEP(xpB, tkB, t + 5)
    }
#undef STEP
#undef FMAK

    // head: out[b] = sigmoid(h . Wd + bd)
    if (tid < 128) {
        const int bb   = tid >> 6;
        const int lane = tid & 63;
        const float* hb = hbuf[bb];
        float v = hb[lane] * Wd[lane] + hb[lane + 64] * Wd[lane + 64];
#pragma unroll
        for (int off = 32; off > 0; off >>= 1)
            v += __shfl_down(v, off, 64);
        if (lane == 0)
            out[b0 + bb] = 1.0f / (1.0f + expf(-(v + bd[0])));
    }
}

extern "C" void kernel_launch(void* const* d_in, const int* in_sizes, int n_in,
                              void* d_out, int out_size, void* d_ws, size_t ws_size,
                              hipStream_t stream)
{
    const int*   X  = (const int*)d_in[0];
    const float* E  = (const float*)d_in[1];
    const float* Wx = (const float*)d_in[2];
    const float* Wh = (const float*)d_in[3];
    const float* b  = (const float*)d_in[4];
    const float* Wd = (const float*)d_in[5];
    const float* bd = (const float*)d_in[6];
    float* out = (float*)d_out;
    float* EWx = (float*)d_ws;   // 30000*128*4 = 15.36 MB scratch

    ewx_kernel<<<dim3((VOCAB + 63) / 64), dim3(256), 0, stream>>>(E, Wx, b, EWx);
    rnn_kernel<<<dim3(BATCH / 2), dim3(256), 0, stream>>>(X, EWx, Wh, Wd, bd, out);
}